// Round 4
// baseline (224.515 us; speedup 1.0000x reference)
//
#include <hip/hip_runtime.h>

// Problem constants (from reference): H=8, D=128 -> 1024 floats per (token,allheads) row
// PAGE=16 slots per page; cache layout [npages][2][PAGE][H][D] fp32.
#define PAGE_SZ 16
#define ROW_F4 256               // (H*D)/4 float4 per row
#define PAGE_F4 8192             // 2*PAGE_SZ*ROW_F4 float4 per page
#define ELEMS_PER_PAGE 32768     // floats per page

typedef float f32x4 __attribute__((ext_vector_type(4)));

// map[p] = (-1, _)        : page untouched by append
//          ( 1, t_base)   : page fully covered; slot s sources token t_base+s
//          ( 2, (b<<20)|j): page partially covered; recompute per-slot
__global__ void init_map_kernel(int2* __restrict__ map, int npages) {
    int i = blockIdx.x * blockDim.x + threadIdx.x;
    if (i < npages) map[i] = make_int2(-1, 0);
}

__global__ void fill_map_kernel(const int* __restrict__ append_indptr,
                                const int* __restrict__ page_indices,
                                const int* __restrict__ page_indptr,
                                const int* __restrict__ lastlen,
                                int2* __restrict__ map,
                                int B, int max_entries) {
    int idx = blockIdx.x * blockDim.x + threadIdx.x;
    if (idx >= max_entries) return;
    if (idx >= page_indptr[B]) return;        // beyond used page entries
    int b = 0;
    while (page_indptr[b + 1] <= idx) b++;
    int j         = idx - page_indptr[b];
    int num_pages = page_indptr[b + 1] - page_indptr[b];
    int num_new   = append_indptr[b + 1] - append_indptr[b];
    int seq_len   = (num_pages - 1) * PAGE_SZ + lastlen[b];
    int start     = seq_len - num_new;        // first appended logical position
    int pos0      = j * PAGE_SZ;
    int lo = pos0 > start ? pos0 : start;
    int hi = (pos0 + PAGE_SZ) < seq_len ? (pos0 + PAGE_SZ) : seq_len;
    if (lo >= hi) return;                     // no new tokens land in this page
    int p = page_indices[idx];
    if (pos0 >= start && pos0 + PAGE_SZ <= seq_len) {
        map[p] = make_int2(1, append_indptr[b] + pos0 - start);   // full page
    } else {
        map[p] = make_int2(2, (b << 20) | j);                     // partial page
    }
}

struct GatherArgs {
    const f32x4* k;
    const f32x4* v;
    const f32x4* cache_in;
    const int* append_indptr;
    const int* page_indptr;
    const int* lastlen;
    const int2* map;
};

__device__ __forceinline__ f32x4 load_src(long e4, const GatherArgs& a) {
    int page = (int)(e4 >> 13);               // / PAGE_F4
    int2 m = a.map[page];
    if (m.x < 0) return a.cache_in[e4];       // untouched page
    int row  = (int)((e4 >> 8) & 31);         // / ROW_F4, % 32
    int slot = row & 15;
    const f32x4* src = (row >> 4) ? a.v : a.k;
    if (m.x == 1) {                           // fully appended page
        return src[((long)(m.y + slot) << 8) | (e4 & 255)];
    }
    // partial page (rare)
    int b = m.y >> 20, j = m.y & 0xFFFFF;
    int num_pages = a.page_indptr[b + 1] - a.page_indptr[b];
    int num_new   = a.append_indptr[b + 1] - a.append_indptr[b];
    int seq_len   = (num_pages - 1) * PAGE_SZ + a.lastlen[b];
    int start     = seq_len - num_new;
    int pos       = j * PAGE_SZ + slot;
    if (pos >= start && pos < seq_len) {
        return src[((long)(a.append_indptr[b] + pos - start) << 8) | (e4 & 255)];
    }
    return a.cache_in[e4];
}

// Grid-stride copy-style gather, modeled on the float4-copy BW pattern:
// moderate grid, plain cached loads/stores, 4 independent loads in flight.
__global__ void __launch_bounds__(256)
gather_stride_kernel(GatherArgs a, f32x4* __restrict__ out, long total) {
    const long stride = (long)gridDim.x * blockDim.x;
    long e = (long)blockIdx.x * blockDim.x + threadIdx.x;
    for (; e + 3 * stride < total; e += 4 * stride) {
        f32x4 v0 = load_src(e,              a);
        f32x4 v1 = load_src(e +     stride, a);
        f32x4 v2 = load_src(e + 2 * stride, a);
        f32x4 v3 = load_src(e + 3 * stride, a);
        out[e]              = v0;
        out[e +     stride] = v1;
        out[e + 2 * stride] = v2;
        out[e + 3 * stride] = v3;
    }
    for (; e < total; e += stride) out[e] = load_src(e, a);
}

extern "C" void kernel_launch(void* const* d_in, const int* in_sizes, int n_in,
                              void* d_out, int out_size, void* d_ws, size_t ws_size,
                              hipStream_t stream) {
    GatherArgs a;
    a.k        = (const f32x4*)d_in[0];
    a.v        = (const f32x4*)d_in[1];
    a.cache_in = (const f32x4*)d_in[2];
    a.append_indptr = (const int*)d_in[3];
    const int* page_indices = (const int*)d_in[4];
    a.page_indptr   = (const int*)d_in[5];
    a.lastlen       = (const int*)d_in[6];
    // d_in[7] is page_size (=16), hard-coded as PAGE_SZ per reference constants.

    int B           = in_sizes[3] - 1;         // 8
    int max_entries = in_sizes[4];             // 2048
    int npages      = (int)((long)out_size / ELEMS_PER_PAGE);  // 4096
    long total_f4   = (long)out_size / 4;      // 33.5M float4

    int2* map = (int2*)d_ws;                   // npages * 8 bytes = 32 KiB
    a.map = map;

    init_map_kernel<<<(npages + 255) / 256, 256, 0, stream>>>(map, npages);
    fill_map_kernel<<<(max_entries + 255) / 256, 256, 0, stream>>>(
        a.append_indptr, page_indices, a.page_indptr, a.lastlen, map, B, max_entries);
    gather_stride_kernel<<<2048, 256, 0, stream>>>(a, (f32x4*)d_out, total_f4);
}

// Round 5
// 217.039 us; speedup vs baseline: 1.0344x; 1.0344x over previous
//
#include <hip/hip_runtime.h>

// Problem constants (from reference): H=8, D=128 -> 1024 floats per (token,allheads) row
// PAGE=16 slots per page; cache layout [npages][2][PAGE][H][D] fp32.
#define PAGE_SZ 16
#define ROW_F4 256               // (H*D)/4 float4 per row
#define PAGE_F4 8192             // 2*PAGE_SZ*ROW_F4 float4 per page
#define ELEMS_PER_PAGE 32768     // floats per page

typedef float f32x4 __attribute__((ext_vector_type(4)));

// map[p] = (-1, _)        : page untouched by append
//          ( 1, t_base)   : page fully covered; slot s sources token t_base+s
//          ( 2, (b<<20)|j): page partially covered; recompute per-slot
__global__ void init_map_kernel(int2* __restrict__ map, int npages) {
    int i = blockIdx.x * blockDim.x + threadIdx.x;
    if (i < npages) map[i] = make_int2(-1, 0);
}

__global__ void fill_map_kernel(const int* __restrict__ append_indptr,
                                const int* __restrict__ page_indices,
                                const int* __restrict__ page_indptr,
                                const int* __restrict__ lastlen,
                                int2* __restrict__ map,
                                int B, int max_entries) {
    int idx = blockIdx.x * blockDim.x + threadIdx.x;
    if (idx >= max_entries) return;
    if (idx >= page_indptr[B]) return;        // beyond used page entries
    int b = 0;
    while (page_indptr[b + 1] <= idx) b++;
    int j         = idx - page_indptr[b];
    int num_pages = page_indptr[b + 1] - page_indptr[b];
    int num_new   = append_indptr[b + 1] - append_indptr[b];
    int seq_len   = (num_pages - 1) * PAGE_SZ + lastlen[b];
    int start     = seq_len - num_new;        // first appended logical position
    int pos0      = j * PAGE_SZ;
    int lo = pos0 > start ? pos0 : start;
    int hi = (pos0 + PAGE_SZ) < seq_len ? (pos0 + PAGE_SZ) : seq_len;
    if (lo >= hi) return;                     // no new tokens land in this page
    int p = page_indices[idx];
    if (pos0 >= start && pos0 + PAGE_SZ <= seq_len) {
        map[p] = make_int2(1, append_indptr[b] + pos0 - start);   // full page
    } else {
        map[p] = make_int2(2, (b << 20) | j);                     // partial page
    }
}

// One block per 4-row group (grid = npages*8): 131K waves of TLP, and within
// each block the 4 loads are unconditional inside one uniform branch path ->
// ILP=4. Map lookup amortized over 4 rows. Plain cached loads/stores.
__global__ void __launch_bounds__(256)
gather_rg_kernel(const f32x4* __restrict__ k,
                 const f32x4* __restrict__ v,
                 const f32x4* __restrict__ cache_in,
                 const int* __restrict__ append_indptr,
                 const int* __restrict__ page_indptr,
                 const int* __restrict__ lastlen,
                 const int2* __restrict__ map,
                 f32x4* __restrict__ out) {
    const int bid  = blockIdx.x;
    const int page = bid >> 3;
    const int rg   = bid & 7;                 // rows rg*4 .. rg*4+3
    const int row0 = rg << 2;
    const int tid  = threadIdx.x;
    const long base = (long)page * PAGE_F4 + (long)row0 * ROW_F4 + tid;

    int2 m = map[page];

    if (m.x == 1) {
        // Fully appended page; rows in this group are all K (rg<4) or all V.
        const f32x4* src = (rg >= 4) ? v : k;
        const int slot0 = row0 & 15;
        const long tb = ((long)(m.y + slot0)) << 8;   // * ROW_F4, contiguous tokens
        f32x4 a0 = src[tb       + tid];
        f32x4 a1 = src[tb + 256 + tid];
        f32x4 a2 = src[tb + 512 + tid];
        f32x4 a3 = src[tb + 768 + tid];
        out[base      ] = a0;
        out[base + 256] = a1;
        out[base + 512] = a2;
        out[base + 768] = a3;
    } else if (m.x < 0) {
        // Untouched page: straight copy.
        f32x4 a0 = cache_in[base      ];
        f32x4 a1 = cache_in[base + 256];
        f32x4 a2 = cache_in[base + 512];
        f32x4 a3 = cache_in[base + 768];
        out[base      ] = a0;
        out[base + 256] = a1;
        out[base + 512] = a2;
        out[base + 768] = a3;
    } else {
        // Partially covered page (rare): per-row decision.
        int b = m.y >> 20, j = m.y & 0xFFFFF;
        int num_pages = page_indptr[b + 1] - page_indptr[b];
        int num_new   = append_indptr[b + 1] - append_indptr[b];
        int seq_len   = (num_pages - 1) * PAGE_SZ + lastlen[b];
        int start     = seq_len - num_new;
        const f32x4* src = (rg >= 4) ? v : k;
        #pragma unroll
        for (int i = 0; i < 4; ++i) {
            int slot = (row0 + i) & 15;
            int pos  = j * PAGE_SZ + slot;
            long e4  = base + (long)i * ROW_F4;
            f32x4 val;
            if (pos >= start && pos < seq_len) {
                val = src[((long)(append_indptr[b] + pos - start) << 8) + tid];
            } else {
                val = cache_in[e4];
            }
            out[e4] = val;
        }
    }
}

extern "C" void kernel_launch(void* const* d_in, const int* in_sizes, int n_in,
                              void* d_out, int out_size, void* d_ws, size_t ws_size,
                              hipStream_t stream) {
    const f32x4* k        = (const f32x4*)d_in[0];
    const f32x4* v        = (const f32x4*)d_in[1];
    const f32x4* cache_in = (const f32x4*)d_in[2];
    const int* append_indptr = (const int*)d_in[3];
    const int* page_indices  = (const int*)d_in[4];
    const int* page_indptr   = (const int*)d_in[5];
    const int* lastlen       = (const int*)d_in[6];
    // d_in[7] is page_size (=16), hard-coded as PAGE_SZ per reference constants.

    int B           = in_sizes[3] - 1;         // 8
    int max_entries = in_sizes[4];             // 2048
    int npages      = (int)((long)out_size / ELEMS_PER_PAGE);  // 4096

    int2* map = (int2*)d_ws;                   // npages * 8 bytes = 32 KiB

    init_map_kernel<<<(npages + 255) / 256, 256, 0, stream>>>(map, npages);
    fill_map_kernel<<<(max_entries + 255) / 256, 256, 0, stream>>>(
        append_indptr, page_indices, page_indptr, lastlen, map, B, max_entries);
    gather_rg_kernel<<<npages * 8, 256, 0, stream>>>(
        k, v, cache_in, append_indptr, page_indptr, lastlen, map,
        (f32x4*)d_out);
}

// Round 6
// 173.019 us; speedup vs baseline: 1.2976x; 1.2544x over previous
//
#include <hip/hip_runtime.h>

// Problem constants (from reference): H=8, D=128 -> 1024 floats per (token,allheads) row
// PAGE=16 slots per page; cache layout [npages][2][PAGE][H][D] fp32.
#define PAGE_SZ 16
#define ROW_F4 256               // (H*D)/4 float4 per row
#define ROWS_PER_PAGE 32         // 2*PAGE_SZ
#define ELEMS_PER_PAGE 32768     // floats per page

typedef float f32x4 __attribute__((ext_vector_type(4)));

// map[p] = (-1, _)        : page untouched by append
//          ( 1, t_base)   : page fully covered; slot s sources token t_base+s
//          ( 2, (b<<20)|j): page partially covered; recompute per-slot
__global__ void init_map_kernel(int2* __restrict__ map, int npages) {
    int i = blockIdx.x * blockDim.x + threadIdx.x;
    if (i < npages) map[i] = make_int2(-1, 0);
}

__global__ void fill_map_kernel(const int* __restrict__ append_indptr,
                                const int* __restrict__ page_indices,
                                const int* __restrict__ page_indptr,
                                const int* __restrict__ lastlen,
                                int2* __restrict__ map,
                                int B, int max_entries) {
    int idx = blockIdx.x * blockDim.x + threadIdx.x;
    if (idx >= max_entries) return;
    if (idx >= page_indptr[B]) return;        // beyond used page entries
    int b = 0;
    while (page_indptr[b + 1] <= idx) b++;
    int j         = idx - page_indptr[b];
    int num_pages = page_indptr[b + 1] - page_indptr[b];
    int num_new   = append_indptr[b + 1] - append_indptr[b];
    int seq_len   = (num_pages - 1) * PAGE_SZ + lastlen[b];
    int start     = seq_len - num_new;        // first appended logical position
    int pos0      = j * PAGE_SZ;
    int lo = pos0 > start ? pos0 : start;
    int hi = (pos0 + PAGE_SZ) < seq_len ? (pos0 + PAGE_SZ) : seq_len;
    if (lo >= hi) return;                     // no new tokens land in this page
    int p = page_indices[idx];
    if (pos0 >= start && pos0 + PAGE_SZ <= seq_len) {
        map[p] = make_int2(1, append_indptr[b] + pos0 - start);   // full page
    } else {
        map[p] = make_int2(2, (b << 20) | j);                     // partial page
    }
}

// One block per (page, kv, slot) row: 256 threads x float4 = 4 KiB, coalesced.
// R1 structure (best known: max TLP, 1 load + 1 store per thread) with
// nontemporal hints added on all touch-once streams.
__global__ void __launch_bounds__(256)
gather_kernel(const f32x4* __restrict__ k,
              const f32x4* __restrict__ v,
              const f32x4* __restrict__ cache_in,
              const int* __restrict__ append_indptr,
              const int* __restrict__ page_indptr,
              const int* __restrict__ lastlen,
              const int2* __restrict__ map,
              f32x4* __restrict__ out) {
    int bid   = blockIdx.x;
    int page  = bid >> 5;          // /ROWS_PER_PAGE
    int row   = bid & 31;
    int kvsel = row >> 4;
    int slot  = row & 15;
    int tid   = threadIdx.x;       // float4 index within row
    long e4   = (long)bid * ROW_F4 + tid;

    int2 m = map[page];
    f32x4 val;
    if (m.x == 1) {
        long t = (long)(m.y + slot);
        const f32x4* src = kvsel ? v : k;
        val = __builtin_nontemporal_load(&src[t * ROW_F4 + tid]);
    } else if (m.x < 0) {
        val = __builtin_nontemporal_load(&cache_in[e4]);
    } else {
        int b = m.y >> 20, j = m.y & 0xFFFFF;
        int num_pages = page_indptr[b + 1] - page_indptr[b];
        int num_new   = append_indptr[b + 1] - append_indptr[b];
        int seq_len   = (num_pages - 1) * PAGE_SZ + lastlen[b];
        int start     = seq_len - num_new;
        int pos       = j * PAGE_SZ + slot;
        if (pos >= start && pos < seq_len) {
            long t = (long)(append_indptr[b] + pos - start);
            const f32x4* src = kvsel ? v : k;
            val = __builtin_nontemporal_load(&src[t * ROW_F4 + tid]);
        } else {
            val = __builtin_nontemporal_load(&cache_in[e4]);
        }
    }
    __builtin_nontemporal_store(val, &out[e4]);
}

extern "C" void kernel_launch(void* const* d_in, const int* in_sizes, int n_in,
                              void* d_out, int out_size, void* d_ws, size_t ws_size,
                              hipStream_t stream) {
    const f32x4* k        = (const f32x4*)d_in[0];
    const f32x4* v        = (const f32x4*)d_in[1];
    const f32x4* cache_in = (const f32x4*)d_in[2];
    const int* append_indptr = (const int*)d_in[3];
    const int* page_indices  = (const int*)d_in[4];
    const int* page_indptr   = (const int*)d_in[5];
    const int* lastlen       = (const int*)d_in[6];
    // d_in[7] is page_size (=16), hard-coded as PAGE_SZ per reference constants.

    int B           = in_sizes[3] - 1;         // 8
    int max_entries = in_sizes[4];             // 2048
    int npages      = (int)((long)out_size / ELEMS_PER_PAGE);  // 4096

    int2* map = (int2*)d_ws;                   // npages * 8 bytes = 32 KiB

    init_map_kernel<<<(npages + 255) / 256, 256, 0, stream>>>(map, npages);
    fill_map_kernel<<<(max_entries + 255) / 256, 256, 0, stream>>>(
        append_indptr, page_indices, page_indptr, lastlen, map, B, max_entries);
    gather_kernel<<<npages * ROWS_PER_PAGE, 256, 0, stream>>>(
        k, v, cache_in, append_indptr, page_indptr, lastlen, map,
        (f32x4*)d_out);
}